// Round 1
// baseline (1113.307 us; speedup 1.0000x reference)
//
#include <hip/hip_runtime.h>
#include <math.h>

#define BLK 256

// ---------------------------------------------------------------------------
// Phase 1: per-face axis index (argmax of face normal vs 6 axes) + global max
// of |selected coord| per corner slot (max_dim_div, shape (1,3)).
// ---------------------------------------------------------------------------
__global__ void k_phase1(const float* __restrict__ vp,
                         const float* __restrict__ vn,
                         const int*   __restrict__ tri,
                         const float* __restrict__ bbox,
                         float*       __restrict__ out_index,   // written as float
                         unsigned int* __restrict__ ws_md,      // 3 slots, uint-bits of nonneg float
                         int nf)
{
    int f = blockIdx.x * blockDim.x + threadIdx.x;
    float m0 = 0.f, m1 = 0.f, m2 = 0.f;
    if (f < nf) {
        int i0 = tri[3 * f + 0], i1 = tri[3 * f + 1], i2 = tri[3 * f + 2];

        // face normal = sum of vertex normals, sequential order (v0+v1)+v2,
        // replicated bit-exactly (no fma contraction) since argmax must match.
        float nx = __fadd_rn(__fadd_rn(vn[3 * i0 + 0], vn[3 * i1 + 0]), vn[3 * i2 + 0]);
        float ny = __fadd_rn(__fadd_rn(vn[3 * i0 + 1], vn[3 * i1 + 1]), vn[3 * i2 + 1]);
        float nz = __fadd_rn(__fadd_rn(vn[3 * i0 + 2], vn[3 * i1 + 2]), vn[3 * i2 + 2]);
        float s  = __fadd_rn(__fadd_rn(__fmul_rn(nx, nx), __fmul_rn(ny, ny)), __fmul_rn(nz, nz));
        float nrm = __fsqrt_rn(s);
        float dv  = fmaxf(nrm, 1e-6f);
        float cx = __fdiv_rn(nx, dv);
        float cy = __fdiv_rn(ny, dv);
        float cz = __fdiv_rn(nz, dv);

        // argmax over [cx,-cx,cy,-cy,cz,-cz], first-max wins (strict >)
        float d[6] = {cx, -cx, cy, -cy, cz, -cz};
        int index = 0;
        float best = d[0];
#pragma unroll
        for (int a = 1; a < 6; ++a) {
            if (d[a] > best) { best = d[a]; index = a; }
        }
        out_index[f] = (float)index;

        float b0x = bbox[0], b0y = bbox[1], b0z = bbox[2];
        float b1x = bbox[3], b1y = bbox[4], b1z = bbox[5];

        int idxs[3] = {i0, i1, i2};
        float m[3];
#pragma unroll
        for (int j = 0; j < 3; ++j) {
            int iv = idxs[j];
            float vx = 2.0f * (vp[3 * iv + 0] - b0x) / (b1x - b0x) - 1.0f;
            float vy = 2.0f * (vp[3 * iv + 1] - b0y) / (b1y - b0y) - 1.0f;
            float vz = 2.0f * (vp[3 * iv + 2] - b0z) / (b1z - b0z) - 1.0f;
            m[j] = (index <= 1) ? fabsf(vx) : ((index <= 3) ? fabsf(vy) : fabsf(vz));
        }
        m0 = m[0]; m1 = m[1]; m2 = m[2];
    }

    // wave-64 max reduce, then one atomicMax per wave per slot.
    // values are nonnegative floats -> uint bit-pattern order == float order.
#pragma unroll
    for (int off = 32; off > 0; off >>= 1) {
        m0 = fmaxf(m0, __shfl_down(m0, off, 64));
        m1 = fmaxf(m1, __shfl_down(m1, off, 64));
        m2 = fmaxf(m2, __shfl_down(m2, off, 64));
    }
    if ((threadIdx.x & 63) == 0) {
        atomicMax(&ws_md[0], __float_as_uint(m0));
        atomicMax(&ws_md[1], __float_as_uint(m1));
        atomicMax(&ws_md[2], __float_as_uint(m2));
    }
}

// ---------------------------------------------------------------------------
// Phase 2: per-face uv (needs global max_dim_div) + tangent scatter-add.
// ---------------------------------------------------------------------------
__global__ void k_phase2(const float* __restrict__ vp,
                         const int*   __restrict__ tri,
                         const float* __restrict__ bbox,
                         const float* __restrict__ out_index,
                         const unsigned int* __restrict__ ws_md,
                         float* __restrict__ out_uv,
                         float* __restrict__ tan_acc,   // NV*3, pre-zeroed (aliases out tangent region)
                         float* __restrict__ count,     // NV, pre-zeroed
                         int nf)
{
    int f = blockIdx.x * blockDim.x + threadIdx.x;
    if (f >= nf) return;

    int i0 = tri[3 * f + 0], i1 = tri[3 * f + 1], i2 = tri[3 * f + 2];
    int idxs[3] = {i0, i1, i2};
    int index = (int)out_index[f];

    float md[3];
    md[0] = __uint_as_float(ws_md[0]);
    md[1] = __uint_as_float(ws_md[1]);
    md[2] = __uint_as_float(ws_md[2]);

    float b0x = bbox[0], b0y = bbox[1], b0z = bbox[2];
    float b1x = bbox[3], b1y = bbox[4], b1z = bbox[5];

    float px[3], py[3], pz[3];
    float uc[3], vc[3];
#pragma unroll
    for (int j = 0; j < 3; ++j) {
        int iv = idxs[j];
        px[j] = vp[3 * iv + 0];
        py[j] = vp[3 * iv + 1];
        pz[j] = vp[3 * iv + 2];
        float vx = 2.0f * (px[j] - b0x) / (b1x - b0x) - 1.0f;
        float vy = 2.0f * (py[j] - b0y) / (b1y - b0y) - 1.0f;
        float vz = 2.0f * (pz[j] - b0z) / (b1z - b0z) - 1.0f;

        float ur = (index <= 1) ? vy : vx;
        float vr = (index <= 3) ? (-vz) : ((index == 4) ? vy : (-vy));

        float u = fminf(fmaxf((ur / md[j] + 1.0f) * 0.5f, 0.0f), 1.0f);
        float v = fminf(fmaxf((vr / md[j] + 1.0f) * 0.5f, 0.0f), 1.0f);
        uc[j] = u; vc[j] = v;
        out_uv[(size_t)6 * f + 2 * j + 0] = u;
        out_uv[(size_t)6 * f + 2 * j + 1] = v;
    }

    float duv1x = uc[1] - uc[0], duv1y = vc[1] - vc[0];
    float duv2x = uc[2] - uc[0], duv2y = vc[2] - vc[0];
    float dp1x = px[1] - px[0], dp1y = py[1] - py[0], dp1z = pz[1] - pz[0];
    float dp2x = px[2] - px[0], dp2y = py[2] - py[0], dp2z = pz[2] - pz[0];

    float tngx = dp1x * duv2y - dp2x * duv1y;
    float tngy = dp1y * duv2y - dp2y * duv1y;
    float tngz = dp1z * duv2y - dp2z * duv1y;
    float denom = fmaxf(duv1x * duv2y - duv1y * duv2x, 1e-6f);
    float tx = tngx / denom, ty = tngy / denom, tz = tngz / denom;

#pragma unroll
    for (int j = 0; j < 3; ++j) {
        int iv = idxs[j];
        atomicAdd(&tan_acc[3 * iv + 0], tx);
        atomicAdd(&tan_acc[3 * iv + 1], ty);
        atomicAdd(&tan_acc[3 * iv + 2], tz);
        atomicAdd(&count[iv], 1.0f);
    }
}

// ---------------------------------------------------------------------------
// Phase 3: per-vertex normalize + Gram-Schmidt vs vertex normal.
// ---------------------------------------------------------------------------
__global__ void k_phase3(const float* __restrict__ vn,
                         const float* __restrict__ count,
                         float* __restrict__ tan_io,   // in: accumulated sums, out: final tangents
                         int nv)
{
    int v = blockIdx.x * blockDim.x + threadIdx.x;
    if (v >= nv) return;

    float c = count[v];
    float tx = tan_io[3 * v + 0] / c;
    float ty = tan_io[3 * v + 1] / c;
    float tz = tan_io[3 * v + 2] / c;

    float n1 = sqrtf(tx * tx + ty * ty + tz * tz);
    float inv1 = 1.0f / fmaxf(n1, 1e-12f);
    tx *= inv1; ty *= inv1; tz *= inv1;

    float nx = vn[3 * v + 0], ny = vn[3 * v + 1], nz = vn[3 * v + 2];
    float d = tx * nx + ty * ny + tz * nz;
    tx -= d * nx; ty -= d * ny; tz -= d * nz;

    float n2 = sqrtf(tx * tx + ty * ty + tz * tz);
    float inv2 = 1.0f / fmaxf(n2, 1e-12f);

    tan_io[3 * v + 0] = tx * inv2;
    tan_io[3 * v + 1] = ty * inv2;
    tan_io[3 * v + 2] = tz * inv2;
}

extern "C" void kernel_launch(void* const* d_in, const int* in_sizes, int n_in,
                              void* d_out, int out_size, void* d_ws, size_t ws_size,
                              hipStream_t stream)
{
    const float* vp   = (const float*)d_in[0];
    const float* vn   = (const float*)d_in[1];
    const int*   tri  = (const int*)d_in[2];
    const float* bbox = (const float*)d_in[3];

    const int nv = in_sizes[0] / 3;
    const int nf = in_sizes[2] / 3;

    float* out_uv    = (float*)d_out;
    float* out_index = out_uv + (size_t)nf * 6;
    float* out_tan   = out_index + nf;

    unsigned int* ws_md = (unsigned int*)d_ws;      // 4 slots (3 used)
    float* ws_count     = (float*)d_ws + 4;         // NV floats

    // zero the reduction targets (ws is poisoned 0xAA once before timing,
    // and nothing is re-poisoned between replays -> must re-zero every call)
    hipMemsetAsync(ws_md, 0, 4 * sizeof(unsigned int) + (size_t)nv * sizeof(float), stream);
    hipMemsetAsync(out_tan, 0, (size_t)nv * 3 * sizeof(float), stream);

    int nbf = (nf + BLK - 1) / BLK;
    int nbv = (nv + BLK - 1) / BLK;

    k_phase1<<<nbf, BLK, 0, stream>>>(vp, vn, tri, bbox, out_index, ws_md, nf);
    k_phase2<<<nbf, BLK, 0, stream>>>(vp, tri, bbox, out_index, ws_md,
                                      out_uv, out_tan, ws_count, nf);
    k_phase3<<<nbv, BLK, 0, stream>>>(vn, ws_count, out_tan, nv);
}

// Round 2
// 710.805 us; speedup vs baseline: 1.5663x; 1.5663x over previous
//
#include <hip/hip_runtime.h>
#include <math.h>

#define BLK 256

// ===========================================================================
// FAST PATH (needs ~52MB ws): packed vertex table + per-face SoA spill
// ===========================================================================

// Build packed per-vertex record (32B): [vn.x, vn.y, vn.z, v.x][v.y, v.z, -, -]
// where v = 2*(vp-b0)/(b1-b0)-1. Also zeroes tangent accumulator + ws_md.
__global__ void k_build(const float* __restrict__ vp,
                        const float* __restrict__ vn,
                        const float* __restrict__ bbox,
                        float* __restrict__ packed,
                        float* __restrict__ out_tan,
                        unsigned int* __restrict__ ws_md,
                        int nv)
{
    int v = blockIdx.x * blockDim.x + threadIdx.x;
    if (v == 0) { ws_md[0] = 0u; ws_md[1] = 0u; ws_md[2] = 0u; ws_md[3] = 0u; }
    if (v >= nv) return;

    float b0x = bbox[0], b0y = bbox[1], b0z = bbox[2];
    float b1x = bbox[3], b1y = bbox[4], b1z = bbox[5];
    float nx = vn[3 * v + 0], ny = vn[3 * v + 1], nz = vn[3 * v + 2];
    float px = vp[3 * v + 0], py = vp[3 * v + 1], pz = vp[3 * v + 2];
    float vx = 2.0f * (px - b0x) / (b1x - b0x) - 1.0f;
    float vy = 2.0f * (py - b0y) / (b1y - b0y) - 1.0f;
    float vz = 2.0f * (pz - b0z) / (b1z - b0z) - 1.0f;

    float4* dst = (float4*)(packed + (size_t)8 * v);
    dst[0] = make_float4(nx, ny, nz, vx);
    dst[1] = make_float4(vy, vz, 0.f, 0.f);

    out_tan[3 * v + 0] = 0.f;
    out_tan[3 * v + 1] = 0.f;
    out_tan[3 * v + 2] = 0.f;
}

// Phase A: per-face index (exact argmax chain) + md reduction + spill coords.
// 2 faces/thread (t, t+half) for extra MLP; all gathers are single-line 32B.
__global__ void k_faceA(const int* __restrict__ tri,
                        const float* __restrict__ packed,
                        float* __restrict__ out_index,
                        float* __restrict__ faceV,   // 9 SoA streams of length nf
                        unsigned int* __restrict__ ws_md,
                        int nf, int half)
{
    int t = blockIdx.x * blockDim.x + threadIdx.x;
    float mm0 = 0.f, mm1 = 0.f, mm2 = 0.f;

#pragma unroll
    for (int rep = 0; rep < 2; ++rep) {
        int f = t + rep * half;
        if (t < half && f < nf) {
            int i0 = tri[3 * f + 0], i1 = tri[3 * f + 1], i2 = tri[3 * f + 2];
            float4 a0 = *(const float4*)(packed + (size_t)8 * i0);
            float4 c0 = *(const float4*)(packed + (size_t)8 * i0 + 4);
            float4 a1 = *(const float4*)(packed + (size_t)8 * i1);
            float4 c1 = *(const float4*)(packed + (size_t)8 * i1 + 4);
            float4 a2 = *(const float4*)(packed + (size_t)8 * i2);
            float4 c2 = *(const float4*)(packed + (size_t)8 * i2 + 4);

            // exact replication of reference argmax chain
            float nx = __fadd_rn(__fadd_rn(a0.x, a1.x), a2.x);
            float ny = __fadd_rn(__fadd_rn(a0.y, a1.y), a2.y);
            float nz = __fadd_rn(__fadd_rn(a0.z, a1.z), a2.z);
            float s  = __fadd_rn(__fadd_rn(__fmul_rn(nx, nx), __fmul_rn(ny, ny)),
                                 __fmul_rn(nz, nz));
            float dv = fmaxf(__fsqrt_rn(s), 1e-6f);
            float cx = __fdiv_rn(nx, dv);
            float cy = __fdiv_rn(ny, dv);
            float cz = __fdiv_rn(nz, dv);
            float d[6] = {cx, -cx, cy, -cy, cz, -cz};
            int index = 0;
            float best = d[0];
#pragma unroll
            for (int a = 1; a < 6; ++a)
                if (d[a] > best) { best = d[a]; index = a; }
            out_index[f] = (float)index;

            float vxs[3] = {a0.w, a1.w, a2.w};
            float vys[3] = {c0.x, c1.x, c2.x};
            float vzs[3] = {c0.y, c1.y, c2.y};

            float m0 = (index <= 1) ? fabsf(vxs[0]) : ((index <= 3) ? fabsf(vys[0]) : fabsf(vzs[0]));
            float m1 = (index <= 1) ? fabsf(vxs[1]) : ((index <= 3) ? fabsf(vys[1]) : fabsf(vzs[1]));
            float m2 = (index <= 1) ? fabsf(vxs[2]) : ((index <= 3) ? fabsf(vys[2]) : fabsf(vzs[2]));
            mm0 = fmaxf(mm0, m0); mm1 = fmaxf(mm1, m1); mm2 = fmaxf(mm2, m2);

            size_t NF = (size_t)nf;
            faceV[0 * NF + f] = vxs[0]; faceV[1 * NF + f] = vys[0]; faceV[2 * NF + f] = vzs[0];
            faceV[3 * NF + f] = vxs[1]; faceV[4 * NF + f] = vys[1]; faceV[5 * NF + f] = vzs[1];
            faceV[6 * NF + f] = vxs[2]; faceV[7 * NF + f] = vys[2]; faceV[8 * NF + f] = vzs[2];
        }
    }

#pragma unroll
    for (int off = 32; off > 0; off >>= 1) {
        mm0 = fmaxf(mm0, __shfl_down(mm0, off, 64));
        mm1 = fmaxf(mm1, __shfl_down(mm1, off, 64));
        mm2 = fmaxf(mm2, __shfl_down(mm2, off, 64));
    }
    if ((threadIdx.x & 63) == 0) {
        atomicMax(&ws_md[0], __float_as_uint(mm0));
        atomicMax(&ws_md[1], __float_as_uint(mm1));
        atomicMax(&ws_md[2], __float_as_uint(mm2));
    }
}

// Phase B: uv + tangent scatter. Zero gathers: everything streamed from faceV.
__global__ void k_faceB(const int* __restrict__ tri,
                        const float* __restrict__ bbox,
                        const float* __restrict__ out_index,
                        const unsigned int* __restrict__ ws_md,
                        const float* __restrict__ faceV,
                        float* __restrict__ out_uv,
                        float* __restrict__ tan_acc,
                        int nf)
{
    int f = blockIdx.x * blockDim.x + threadIdx.x;
    if (f >= nf) return;

    size_t NF = (size_t)nf;
    int index = (int)out_index[f];
    float md[3];
    md[0] = __uint_as_float(ws_md[0]);
    md[1] = __uint_as_float(ws_md[1]);
    md[2] = __uint_as_float(ws_md[2]);

    float vx[3], vy[3], vz[3];
#pragma unroll
    for (int j = 0; j < 3; ++j) {
        vx[j] = faceV[(size_t)(3 * j + 0) * NF + f];
        vy[j] = faceV[(size_t)(3 * j + 1) * NF + f];
        vz[j] = faceV[(size_t)(3 * j + 2) * NF + f];
    }

    float uc[3], vc[3];
#pragma unroll
    for (int j = 0; j < 3; ++j) {
        float ur = (index <= 1) ? vy[j] : vx[j];
        float vr = (index <= 3) ? (-vz[j]) : ((index == 4) ? vy[j] : (-vy[j]));
        float u = fminf(fmaxf((ur / md[j] + 1.0f) * 0.5f, 0.0f), 1.0f);
        float v = fminf(fmaxf((vr / md[j] + 1.0f) * 0.5f, 0.0f), 1.0f);
        uc[j] = u; vc[j] = v;
        out_uv[(size_t)6 * f + 2 * j + 0] = u;
        out_uv[(size_t)6 * f + 2 * j + 1] = v;
    }

    // dpos reconstructed from normalized coord diffs: p = (v+1)*0.5*(b1-b0)+b0
    float sx = 0.5f * (bbox[3] - bbox[0]);
    float sy = 0.5f * (bbox[4] - bbox[1]);
    float sz = 0.5f * (bbox[5] - bbox[2]);

    float duv1x = uc[1] - uc[0], duv1y = vc[1] - vc[0];
    float duv2x = uc[2] - uc[0], duv2y = vc[2] - vc[0];
    float dp1x = sx * (vx[1] - vx[0]), dp1y = sy * (vy[1] - vy[0]), dp1z = sz * (vz[1] - vz[0]);
    float dp2x = sx * (vx[2] - vx[0]), dp2y = sy * (vy[2] - vy[0]), dp2z = sz * (vz[2] - vz[0]);

    float tngx = dp1x * duv2y - dp2x * duv1y;
    float tngy = dp1y * duv2y - dp2y * duv1y;
    float tngz = dp1z * duv2y - dp2z * duv1y;
    float denom = fmaxf(duv1x * duv2y - duv1y * duv2x, 1e-6f);
    float tx = tngx / denom, ty = tngy / denom, tz = tngz / denom;

    int i0 = tri[3 * f + 0], i1 = tri[3 * f + 1], i2 = tri[3 * f + 2];
    int idxs[3] = {i0, i1, i2};
#pragma unroll
    for (int j = 0; j < 3; ++j) {
        int iv = idxs[j];
        atomicAdd(&tan_acc[3 * iv + 0], tx);
        atomicAdd(&tan_acc[3 * iv + 1], ty);
        atomicAdd(&tan_acc[3 * iv + 2], tz);
    }
}

// Final: normalize(t) (count division is direction-neutral, c>=1 always),
// Gram-Schmidt vs vn, normalize.
__global__ void k_final(const float* __restrict__ vn,
                        float* __restrict__ tan_io,
                        int nv)
{
    int v = blockIdx.x * blockDim.x + threadIdx.x;
    if (v >= nv) return;

    float tx = tan_io[3 * v + 0];
    float ty = tan_io[3 * v + 1];
    float tz = tan_io[3 * v + 2];

    float n1 = sqrtf(tx * tx + ty * ty + tz * tz);
    float inv1 = 1.0f / fmaxf(n1, 1e-12f);
    tx *= inv1; ty *= inv1; tz *= inv1;

    float nx = vn[3 * v + 0], ny = vn[3 * v + 1], nz = vn[3 * v + 2];
    float d = tx * nx + ty * ny + tz * nz;
    tx -= d * nx; ty -= d * ny; tz -= d * nz;

    float n2 = sqrtf(tx * tx + ty * ty + tz * tz);
    float inv2 = 1.0f / fmaxf(n2, 1e-12f);

    tan_io[3 * v + 0] = tx * inv2;
    tan_io[3 * v + 1] = ty * inv2;
    tan_io[3 * v + 2] = tz * inv2;
}

// ===========================================================================
// FALLBACK PATH (tiny ws): R0 structure minus count atomics
// ===========================================================================

__global__ void k_phase1_fb(const float* __restrict__ vp,
                            const float* __restrict__ vn,
                            const int*   __restrict__ tri,
                            const float* __restrict__ bbox,
                            float*       __restrict__ out_index,
                            unsigned int* __restrict__ ws_md,
                            int nf)
{
    int f = blockIdx.x * blockDim.x + threadIdx.x;
    float m0 = 0.f, m1 = 0.f, m2 = 0.f;
    if (f < nf) {
        int i0 = tri[3 * f + 0], i1 = tri[3 * f + 1], i2 = tri[3 * f + 2];
        float nx = __fadd_rn(__fadd_rn(vn[3 * i0 + 0], vn[3 * i1 + 0]), vn[3 * i2 + 0]);
        float ny = __fadd_rn(__fadd_rn(vn[3 * i0 + 1], vn[3 * i1 + 1]), vn[3 * i2 + 1]);
        float nz = __fadd_rn(__fadd_rn(vn[3 * i0 + 2], vn[3 * i1 + 2]), vn[3 * i2 + 2]);
        float s  = __fadd_rn(__fadd_rn(__fmul_rn(nx, nx), __fmul_rn(ny, ny)), __fmul_rn(nz, nz));
        float dv = fmaxf(__fsqrt_rn(s), 1e-6f);
        float cx = __fdiv_rn(nx, dv), cy = __fdiv_rn(ny, dv), cz = __fdiv_rn(nz, dv);
        float d[6] = {cx, -cx, cy, -cy, cz, -cz};
        int index = 0; float best = d[0];
#pragma unroll
        for (int a = 1; a < 6; ++a)
            if (d[a] > best) { best = d[a]; index = a; }
        out_index[f] = (float)index;

        float b0x = bbox[0], b0y = bbox[1], b0z = bbox[2];
        float b1x = bbox[3], b1y = bbox[4], b1z = bbox[5];
        int idxs[3] = {i0, i1, i2};
        float m[3];
#pragma unroll
        for (int j = 0; j < 3; ++j) {
            int iv = idxs[j];
            float vx = 2.0f * (vp[3 * iv + 0] - b0x) / (b1x - b0x) - 1.0f;
            float vy = 2.0f * (vp[3 * iv + 1] - b0y) / (b1y - b0y) - 1.0f;
            float vz = 2.0f * (vp[3 * iv + 2] - b0z) / (b1z - b0z) - 1.0f;
            m[j] = (index <= 1) ? fabsf(vx) : ((index <= 3) ? fabsf(vy) : fabsf(vz));
        }
        m0 = m[0]; m1 = m[1]; m2 = m[2];
    }
#pragma unroll
    for (int off = 32; off > 0; off >>= 1) {
        m0 = fmaxf(m0, __shfl_down(m0, off, 64));
        m1 = fmaxf(m1, __shfl_down(m1, off, 64));
        m2 = fmaxf(m2, __shfl_down(m2, off, 64));
    }
    if ((threadIdx.x & 63) == 0) {
        atomicMax(&ws_md[0], __float_as_uint(m0));
        atomicMax(&ws_md[1], __float_as_uint(m1));
        atomicMax(&ws_md[2], __float_as_uint(m2));
    }
}

__global__ void k_phase2_fb(const float* __restrict__ vp,
                            const int*   __restrict__ tri,
                            const float* __restrict__ bbox,
                            const float* __restrict__ out_index,
                            const unsigned int* __restrict__ ws_md,
                            float* __restrict__ out_uv,
                            float* __restrict__ tan_acc,
                            int nf)
{
    int f = blockIdx.x * blockDim.x + threadIdx.x;
    if (f >= nf) return;

    int i0 = tri[3 * f + 0], i1 = tri[3 * f + 1], i2 = tri[3 * f + 2];
    int idxs[3] = {i0, i1, i2};
    int index = (int)out_index[f];

    float md[3];
    md[0] = __uint_as_float(ws_md[0]);
    md[1] = __uint_as_float(ws_md[1]);
    md[2] = __uint_as_float(ws_md[2]);

    float b0x = bbox[0], b0y = bbox[1], b0z = bbox[2];
    float b1x = bbox[3], b1y = bbox[4], b1z = bbox[5];

    float px[3], py[3], pz[3], uc[3], vc[3];
#pragma unroll
    for (int j = 0; j < 3; ++j) {
        int iv = idxs[j];
        px[j] = vp[3 * iv + 0]; py[j] = vp[3 * iv + 1]; pz[j] = vp[3 * iv + 2];
        float vx = 2.0f * (px[j] - b0x) / (b1x - b0x) - 1.0f;
        float vy = 2.0f * (py[j] - b0y) / (b1y - b0y) - 1.0f;
        float vz = 2.0f * (pz[j] - b0z) / (b1z - b0z) - 1.0f;
        float ur = (index <= 1) ? vy : vx;
        float vr = (index <= 3) ? (-vz) : ((index == 4) ? vy : (-vy));
        float u = fminf(fmaxf((ur / md[j] + 1.0f) * 0.5f, 0.0f), 1.0f);
        float v = fminf(fmaxf((vr / md[j] + 1.0f) * 0.5f, 0.0f), 1.0f);
        uc[j] = u; vc[j] = v;
        out_uv[(size_t)6 * f + 2 * j + 0] = u;
        out_uv[(size_t)6 * f + 2 * j + 1] = v;
    }

    float duv1x = uc[1] - uc[0], duv1y = vc[1] - vc[0];
    float duv2x = uc[2] - uc[0], duv2y = vc[2] - vc[0];
    float dp1x = px[1] - px[0], dp1y = py[1] - py[0], dp1z = pz[1] - pz[0];
    float dp2x = px[2] - px[0], dp2y = py[2] - py[0], dp2z = pz[2] - pz[0];

    float tngx = dp1x * duv2y - dp2x * duv1y;
    float tngy = dp1y * duv2y - dp2y * duv1y;
    float tngz = dp1z * duv2y - dp2z * duv1y;
    float denom = fmaxf(duv1x * duv2y - duv1y * duv2x, 1e-6f);
    float tx = tngx / denom, ty = tngy / denom, tz = tngz / denom;

#pragma unroll
    for (int j = 0; j < 3; ++j) {
        int iv = idxs[j];
        atomicAdd(&tan_acc[3 * iv + 0], tx);
        atomicAdd(&tan_acc[3 * iv + 1], ty);
        atomicAdd(&tan_acc[3 * iv + 2], tz);
    }
}

// ===========================================================================

extern "C" void kernel_launch(void* const* d_in, const int* in_sizes, int n_in,
                              void* d_out, int out_size, void* d_ws, size_t ws_size,
                              hipStream_t stream)
{
    const float* vp   = (const float*)d_in[0];
    const float* vn   = (const float*)d_in[1];
    const int*   tri  = (const int*)d_in[2];
    const float* bbox = (const float*)d_in[3];

    const int nv = in_sizes[0] / 3;
    const int nf = in_sizes[2] / 3;

    float* out_uv    = (float*)d_out;
    float* out_index = out_uv + (size_t)nf * 6;
    float* out_tan   = out_index + nf;

    unsigned int* ws_md = (unsigned int*)d_ws;

    size_t packed_off   = 256;
    size_t packed_bytes = (size_t)nv * 32;
    size_t faceV_off    = (packed_off + packed_bytes + 255) & ~(size_t)255;
    size_t faceV_bytes  = (size_t)nf * 9 * sizeof(float);
    size_t need         = faceV_off + faceV_bytes;

    int nbf = (nf + BLK - 1) / BLK;
    int nbv = (nv + BLK - 1) / BLK;

    if (ws_size >= need) {
        float* packed = (float*)((char*)d_ws + packed_off);
        float* faceV  = (float*)((char*)d_ws + faceV_off);
        int half  = (nf + 1) / 2;
        int nbh   = (half + BLK - 1) / BLK;

        k_build<<<nbv, BLK, 0, stream>>>(vp, vn, bbox, packed, out_tan, ws_md, nv);
        k_faceA<<<nbh, BLK, 0, stream>>>(tri, packed, out_index, faceV, ws_md, nf, half);
        k_faceB<<<nbf, BLK, 0, stream>>>(tri, bbox, out_index, ws_md, faceV,
                                         out_uv, out_tan, nf);
        k_final<<<nbv, BLK, 0, stream>>>(vn, out_tan, nv);
    } else {
        hipMemsetAsync(ws_md, 0, 4 * sizeof(unsigned int), stream);
        hipMemsetAsync(out_tan, 0, (size_t)nv * 3 * sizeof(float), stream);
        k_phase1_fb<<<nbf, BLK, 0, stream>>>(vp, vn, tri, bbox, out_index, ws_md, nf);
        k_phase2_fb<<<nbf, BLK, 0, stream>>>(vp, tri, bbox, out_index, ws_md,
                                             out_uv, out_tan, nf);
        k_final<<<nbv, BLK, 0, stream>>>(vn, out_tan, nv);
    }
}